// Round 10
// baseline (184.699 us; speedup 1.0000x reference)
//
#include <hip/hip_runtime.h>
#include <math.h>

#define BB 256
#define NN 512
#define DD 6
#define F_IN 62
#define HH 128
#define ND 7
#define TOTAL (BB*NN)   // 131072
#define OPB 640         // order slots per batch (16-aligned degree buckets, -1 padded)
#define SSTR 640        // sorted-buffer rows per batch
#define GPB 40          // 16-row groups per batch
#define STG 132         // staging row stride (bank-spread)

typedef __bf16 bf16x8 __attribute__((ext_vector_type(8)));
typedef float f32x4 __attribute__((ext_vector_type(4)));

__device__ __forceinline__ unsigned short f2bf(float f) {
    unsigned u = __builtin_bit_cast(unsigned, f);
    u = (u + 0x7FFFu + ((u >> 16) & 1u)) >> 16;
    return (unsigned short)u;
}
__device__ __forceinline__ float lo2f(unsigned x) { return __builtin_bit_cast(float, x << 16); }
__device__ __forceinline__ float hi2f(unsigned x) { return __builtin_bit_cast(float, x & 0xFFFF0000u); }

__device__ __forceinline__ uint4 pack8(const float* s) {
    uint4 r;
    r.x = (unsigned)f2bf(s[0]) | ((unsigned)f2bf(s[1]) << 16);
    r.y = (unsigned)f2bf(s[2]) | ((unsigned)f2bf(s[3]) << 16);
    r.z = (unsigned)f2bf(s[4]) | ((unsigned)f2bf(s[5]) << 16);
    r.w = (unsigned)f2bf(s[6]) | ((unsigned)f2bf(s[7]) << 16);
    return r;
}
__device__ __forceinline__ void unpack_add(float* s, uint4 q) {
    s[0] += lo2f(q.x); s[1] += hi2f(q.x); s[2] += lo2f(q.y); s[3] += hi2f(q.y);
    s[4] += lo2f(q.z); s[5] += hi2f(q.z); s[6] += lo2f(q.w); s[7] += hi2f(q.w);
}
__device__ __forceinline__ void unpack_max(float* s, uint4 q) {
    s[0] = fmaxf(s[0], lo2f(q.x)); s[1] = fmaxf(s[1], hi2f(q.x));
    s[2] = fmaxf(s[2], lo2f(q.y)); s[3] = fmaxf(s[3], hi2f(q.y));
    s[4] = fmaxf(s[4], lo2f(q.z)); s[5] = fmaxf(s[5], hi2f(q.z));
    s[6] = fmaxf(s[6], lo2f(q.w)); s[7] = fmaxf(s[7], hi2f(q.w));
}
__device__ __forceinline__ void rowadd62(float* s, const float* r, int kb) {
    float2 z0 = *(const float2*)(r);     s[0] += z0.x; s[1] += z0.y;
    float2 z1 = *(const float2*)(r + 2); s[2] += z1.x; s[3] += z1.y;
    float2 z2 = *(const float2*)(r + 4); s[4] += z2.x; s[5] += z2.y;
    if (kb < 7) { float2 z3 = *(const float2*)(r + 6); s[6] += z3.x; s[7] += z3.y; }
}

// ---------------- per-batch counting sort by degree, buckets padded to 16; inv map ------------

__global__ __launch_bounds__(512) void k_sort16(const int* __restrict__ e,
                                                int* __restrict__ order,
                                                int* __restrict__ inv,
                                                int* __restrict__ dgrp) {
    __shared__ unsigned int scnt[ND];
    __shared__ unsigned int sbase[ND + 1];
    const int b = blockIdx.x;
    const int t = threadIdx.x;
    if (t < ND) scnt[t] = 0u;
    for (int i = t; i < OPB; i += 512) order[b * OPB + i] = -1;
    __syncthreads();
    int d = 0;
#pragma unroll
    for (int j = 0; j < DD; ++j) d += (e[(b * NN + t) * DD + j] >= 0) ? 1 : 0;
    unsigned rk = atomicAdd(&scnt[d], 1u);
    __syncthreads();
    if (t == 0) {
        unsigned acc = 0;
        for (int k = 0; k < ND; ++k) { sbase[k] = acc; acc += (scnt[k] + 15u) & ~15u; }
        sbase[ND] = acc;
        for (int k = 0; k < ND; ++k)
            for (unsigned g = sbase[k] >> 4; g < (sbase[k + 1] >> 4); ++g)
                dgrp[b * GPB + g] = k;
        for (unsigned g = sbase[ND] >> 4; g < GPB; ++g) dgrp[b * GPB + g] = 0;
    }
    __syncthreads();
    const int slot = (int)(sbase[d] + rk);
    order[b * OPB + slot] = t;
    inv[b * NN + t] = slot;
}

// ---------------- prep: W [ND][F][HH] f32 -> WT [ND][HH][K] bf16 (K-contig, pad) ----------------

__global__ void k_prep_wt(const float* __restrict__ W, unsigned short* __restrict__ WT,
                          int F, int K) {
    int n = blockIdx.x;   // 0..127
    int d = blockIdx.y;   // 0..6
    for (int k = threadIdx.x; k < K; k += 64) {
        float v = (k < F) ? W[((size_t)d * F + k) * HH + n] : 0.f;
        WT[((size_t)d * HH + n) * K + k] = f2bf(v);
    }
}

// ---------------- barrier-free fused gather+conv ----------------------------------------------
// Each wave owns one degree-pure 16-row group (16 sorted slots) x all 128 output cols.
// Gather lands DIRECTLY in A-fragment registers (lane l: slot g*16+(l&15), kb=(l>>4)+4*kk).
// No LDS on the input path; single barrier only for coalesced-store staging.
// KB=8: conv1 (K=64, f32 `a` input). KB=16: conv2 (K=128, bf16 p1 input).
// Grid = 1280 = 5 blocks x 256 batches (XCD-affine); block covers 128 sorted slots.

template<int KB>
__global__ __launch_bounds__(512, 4)
void k_conv_nb(const void* __restrict__ Xin, const int* __restrict__ e,
               const unsigned short* __restrict__ WT, const float* __restrict__ bias,
               const int* __restrict__ order, const int* __restrict__ dgrp,
               unsigned short* __restrict__ Ys) {
    constexpr int K = KB * 8;
    constexpr int KK = KB / 4;                  // A fragments: 2 or 4
    __shared__ unsigned short stg[128 * STG];   // epilogue staging (~33 KB)

    const int t = threadIdx.x;
    const int l = t & 63;
    const int w = t >> 6;
    const int lr = l & 15;
    const int lq = l >> 4;

    const int bi = blockIdx.x;
    const int x8 = bi & 7;
    const int j = bi >> 3;
    const int batch = x8 + 8 * (j / 5);
    const int blk = j % 5;
    const int g = blk * 8 + w;                  // 16-row group in [0, 40)
    const int slot = g * 16 + lr;

    const int v = order[batch * OPB + slot];
    const int d = dgrp[batch * GPB + g];

    int eidx[DD];
    {
        const int* ep = e + ((size_t)batch * NN + (v >= 0 ? v : 0)) * DD;
#pragma unroll
        for (int jj = 0; jj < DD; ++jj) eidx[jj] = (v >= 0) ? ep[jj] : -1;
    }

    // gather-sum straight into A fragments
    bf16x8 af[KK];
#pragma unroll
    for (int kk = 0; kk < KK; ++kk) {
        const int kb = lq + 4 * kk;
        float s[8] = {0.f, 0.f, 0.f, 0.f, 0.f, 0.f, 0.f, 0.f};
        if (v >= 0) {
            if constexpr (KB == 16) {
                const unsigned short* base = (const unsigned short*)Xin
                                             + (size_t)batch * NN * HH + kb * 8;
                unpack_add(s, *(const uint4*)(base + (size_t)v * HH));
#pragma unroll
                for (int jj = 0; jj < DD; ++jj)
                    if (eidx[jj] >= 0)
                        unpack_add(s, *(const uint4*)(base + (size_t)eidx[jj] * HH));
            } else {
                const float* base = (const float*)Xin + (size_t)batch * NN * F_IN + kb * 8;
                rowadd62(s, base + (size_t)v * F_IN, kb);
#pragma unroll
                for (int jj = 0; jj < DD; ++jj)
                    if (eidx[jj] >= 0) rowadd62(s, base + (size_t)eidx[jj] * F_IN, kb);
            }
        }
        uint4 r = pack8(s);
        af[kk] = __builtin_bit_cast(bf16x8, r);
    }

    // MFMA across all 8 column fragments; B streamed from L2-resident WT; epilogue inline
#pragma unroll
    for (int fr = 0; fr < 8; ++fr) {
        const unsigned short* wp = WT + ((size_t)d * HH + fr * 16 + lr) * K + lq * 8;
        f32x4 z = {0.f, 0.f, 0.f, 0.f};
#pragma unroll
        for (int kk = 0; kk < KK; ++kk) {
            bf16x8 bfr = *(const bf16x8*)(wp + kk * 32);
            z = __builtin_amdgcn_mfma_f32_16x16x32_bf16(af[kk], bfr, z, 0, 0, 0);
        }
        const float bv = bias[d * HH + fr * 16 + lr];
#pragma unroll
        for (int r2 = 0; r2 < 4; ++r2) {
            float zz = 1.f / (1.f + __expf(-(z[r2] + bv)));
            stg[(w * 16 + lq * 4 + r2) * STG + fr * 16 + lr] = f2bf(zz);
        }
    }

    __syncthreads();
    // coalesced copy-out of the block's 128 sorted rows (pad rows harmless, never read back)
    for (int u = t; u < 2048; u += 512) {
        const int n = u >> 4;
        const int c8 = (u & 15) * 8;
        uint4 p = *(const uint4*)&stg[n * STG + c8];
        *(uint4*)&Ys[((size_t)batch * SSTR + blk * 128 + n) * HH + c8] = p;
    }
}

// ---------------- pool1: P[v] = max(h1s[inv[v]], h1s[inv[nbr]]), natural output ----------------

__global__ __launch_bounds__(256) void k_pool_bf(const unsigned short* __restrict__ Xs,
                                                 const int* __restrict__ e,
                                                 const int* __restrict__ inv,
                                                 unsigned short* __restrict__ P) {
    const int t = threadIdx.x;
    const int bi = blockIdx.x;
    const int x8 = bi & 7;
    const int j = bi >> 3;
    const int batch = x8 + 8 * (j >> 5);
    const int sub = j & 31;
    const int node = sub * 16 + (t >> 4);
    const int u = batch * NN + node;
    const int c8 = (t & 15) * 8;
    const unsigned short* base = Xs + (size_t)batch * SSTR * HH + c8;
    float m[8];
    {
        uint4 p = *(const uint4*)(base + (size_t)inv[u] * HH);
        m[0] = lo2f(p.x); m[1] = hi2f(p.x); m[2] = lo2f(p.y); m[3] = hi2f(p.y);
        m[4] = lo2f(p.z); m[5] = hi2f(p.z); m[6] = lo2f(p.w); m[7] = hi2f(p.w);
    }
#pragma unroll
    for (int jj = 0; jj < DD; ++jj) {
        int idx = e[u * DD + jj];
        if (idx >= 0) unpack_max(m, *(const uint4*)(base + (size_t)inv[batch * NN + idx] * HH));
    }
    *(uint4*)&P[(size_t)u * HH + c8] = pack8(m);
}

// ---------------- final: pool over h2s (sorted, via inv) + partial sum (32 blocks/batch) -------

__global__ __launch_bounds__(256) void k_pool_sum_part(const unsigned short* __restrict__ Xs,
                                                       const int* __restrict__ e,
                                                       const int* __restrict__ inv,
                                                       float* __restrict__ partial) {
    __shared__ float red[16][HH + 4];
    const int t = threadIdx.x;
    const int bi = blockIdx.x;
    const int x8 = bi & 7;
    const int j = bi >> 3;
    const int b = x8 + 8 * (j >> 5);
    const int chunk = j & 31;
    const int slot = t >> 4;
    const int c8 = (t & 15) * 8;

    const int u = b * NN + chunk * 16 + slot;
    const unsigned short* base = Xs + (size_t)b * SSTR * HH + c8;
    float m[8];
    {
        uint4 p = *(const uint4*)(base + (size_t)inv[u] * HH);
        m[0] = lo2f(p.x); m[1] = hi2f(p.x); m[2] = lo2f(p.y); m[3] = hi2f(p.y);
        m[4] = lo2f(p.z); m[5] = hi2f(p.z); m[6] = lo2f(p.w); m[7] = hi2f(p.w);
    }
#pragma unroll
    for (int jj = 0; jj < DD; ++jj) {
        int idx = e[u * DD + jj];
        if (idx >= 0) unpack_max(m, *(const uint4*)(base + (size_t)inv[b * NN + idx] * HH));
    }
#pragma unroll
    for (int i = 0; i < 8; ++i) red[slot][c8 + i] = m[i];
    __syncthreads();
    if (t < HH) {
        float s = 0.f;
#pragma unroll
        for (int k = 0; k < 16; ++k) s += red[k][t];
        partial[((size_t)b * 32 + chunk) * HH + t] = s;
    }
}

// ---------------- final reduce: out[b][c] = sum of 32 partials (deterministic) ----------------

__global__ __launch_bounds__(256) void k_sum_final(const float* __restrict__ partial,
                                                   float* __restrict__ out) {
    int g = blockIdx.x * 256 + threadIdx.x;   // b*HH + c, 32768 total
    int b = g >> 7;
    int c = g & 127;
    float s = 0.f;
#pragma unroll
    for (int k = 0; k < 32; ++k) s += partial[((size_t)b * 32 + k) * HH + c];
    out[g] = s;
}

// ---------------- launcher ----------------
// ws overlays (lifetimes disjoint):
//   A [0, 42M):    h1s (conv1 out, pool1 in) -> h2s (conv2 out, pool_sum in)   [256][640][128] bf16
//   B [42M, 74M):  p1 (pool1 out, conv2 in) -> partial (4 MB)
//   meta [74M+):   WT0, WT1, order, dgrp, inv   (~77 MB total)

extern "C" void kernel_launch(void* const* d_in, const int* in_sizes, int n_in,
                              void* d_out, int out_size, void* d_ws, size_t ws_size,
                              hipStream_t stream) {
    const float* a  = (const float*)d_in[0];
    const int*   e  = (const int*)d_in[1];
    const float* W0 = (const float*)d_in[2];
    const float* b0 = (const float*)d_in[3];
    const float* W1 = (const float*)d_in[4];
    const float* b1 = (const float*)d_in[5];
    float* out = (float*)d_out;

    char* ws = (char*)d_ws;
    const size_t SA = (size_t)BB * SSTR * HH * 2;   // 41,943,040
    unsigned short* bufA = (unsigned short*)ws;
    unsigned short* bufB = (unsigned short*)(ws + SA);
    float* partial = (float*)bufB;
    char* dp = ws + SA + (size_t)TOTAL * HH * 2;
    unsigned short* WT0 = (unsigned short*)dp;
    unsigned short* WT1 = WT0 + (size_t)ND * HH * 64;
    int* order = (int*)(WT1 + (size_t)ND * HH * 128);
    int* dgrp  = order + (size_t)BB * OPB;
    int* inv   = dgrp + (size_t)BB * GPB;

    hipLaunchKernelGGL(k_sort16, dim3(BB), dim3(NN), 0, stream, e, order, inv, dgrp);
    hipLaunchKernelGGL(k_prep_wt, dim3(HH, ND), dim3(64), 0, stream, W0, WT0, F_IN, 64);
    hipLaunchKernelGGL(k_prep_wt, dim3(HH, ND), dim3(64), 0, stream, W1, WT1, HH, HH);

    hipLaunchKernelGGL((k_conv_nb<8>),  dim3(BB * 5), dim3(512), 0, stream,
                       (const void*)a, e, WT0, b0, order, dgrp, bufA);
    hipLaunchKernelGGL(k_pool_bf, dim3(TOTAL / 16), dim3(256), 0, stream, bufA, e, inv, bufB);
    hipLaunchKernelGGL((k_conv_nb<16>), dim3(BB * 5), dim3(512), 0, stream,
                       (const void*)bufB, e, WT1, b1, order, dgrp, bufA);
    hipLaunchKernelGGL(k_pool_sum_part, dim3(BB * 32), dim3(256), 0, stream, bufA, e, inv, partial);
    hipLaunchKernelGGL(k_sum_final, dim3(BB * HH / 256), dim3(256), 0, stream, partial, out);
}